// Round 3
// baseline (688.794 us; speedup 1.0000x reference)
//
#include <hip/hip_runtime.h>

namespace {

typedef float f32x4 __attribute__((ext_vector_type(4)));
typedef short bf16x8 __attribute__((ext_vector_type(8)));

constexpr float SM_SCALE = 0.08838834764831845f; // 1/sqrt(128)

#define MFMA16(a, b, c) __builtin_amdgcn_mfma_f32_16x16x32_bf16((a), (b), (c), 0, 0, 0)

__device__ __forceinline__ unsigned short bf16_rne(float x) {
  unsigned u = __float_as_uint(x);
  u += 0x7fffu + ((u >> 16) & 1u);
  return (unsigned short)(u >> 16);
}
__device__ __forceinline__ float bf16f(unsigned short h) {
  return __uint_as_float(((unsigned)h) << 16);
}

// ---------------------------------------------------------------------------
// prep_w: W[2048][128] fp32 -> Wt_hi/Wt_lo [3][128][2048] bf16 (transposed).
// 384 blocks x 256 threads.
// ---------------------------------------------------------------------------
__global__ void prep_w(const float* __restrict__ Wq, const float* __restrict__ Wk,
                       const float* __restrict__ Wv,
                       unsigned short* __restrict__ WtH, unsigned short* __restrict__ WtL) {
  const int tg = blockIdx.x * 256 + threadIdx.x;   // 0..98303
  const int mi = tg >> 15;                          // 0=q 1=k 2=v
  const int rem = tg & 32767;
  const int n = rem & 127;
  const int k0 = (rem >> 7) * 8;
  const float* W = (mi == 0) ? Wq : ((mi == 1) ? Wk : Wv);
  unsigned hv[8], lv[8];
#pragma unroll
  for (int e = 0; e < 8; ++e) {
    float xx = W[(size_t)(k0 + e) * 128 + n];
    unsigned short hh = bf16_rne(xx);
    hv[e] = hh;
    lv[e] = bf16_rne(xx - bf16f(hh));
  }
  uint4 uh, ul;
  uh.x = hv[0] | (hv[1] << 16); uh.y = hv[2] | (hv[3] << 16);
  uh.z = hv[4] | (hv[5] << 16); uh.w = hv[6] | (hv[7] << 16);
  ul.x = lv[0] | (lv[1] << 16); ul.y = lv[2] | (lv[3] << 16);
  ul.z = lv[4] | (lv[5] << 16); ul.w = lv[6] | (lv[7] << 16);
  const size_t off = (size_t)mi * 262144 + (size_t)n * 2048 + k0;
  *(uint4*)(WtH + off) = uh;
  *(uint4*)(WtL + off) = ul;
}

// ---------------------------------------------------------------------------
// qkv_gemm: out[M,128] = x[M,2048] @ W + b, split-bf16 3-pass MFMA (fp32-class).
// grid (3, 256), 256 thr = 4 waves (2x2), BM=64 BN=128 BK=64.
// q,k stored as hi/lo bf16 planes [M][128]; v stored TRANSPOSED [B][128][T].
// ---------------------------------------------------------------------------
__global__ __launch_bounds__(256, 3) void qkv_gemm(
    const float* __restrict__ x,
    const unsigned short* __restrict__ WtH, const unsigned short* __restrict__ WtL,
    const float* __restrict__ bq, const float* __restrict__ bk, const float* __restrict__ bv,
    unsigned short* __restrict__ qh, unsigned short* __restrict__ ql,
    unsigned short* __restrict__ kh, unsigned short* __restrict__ kl,
    unsigned short* __restrict__ vTh, unsigned short* __restrict__ vTl) {
  __shared__ __align__(16) unsigned short sm[24576];   // 48 KB
  unsigned short* AsH = sm;            // [64][64] swizzled
  unsigned short* AsL = sm + 4096;
  unsigned short* BsH = sm + 8192;     // [128][64] n-major, swizzled
  unsigned short* BsL = sm + 16384;

  const int mi = blockIdx.x;
  const int m0 = blockIdx.y * 64;
  const int t = threadIdx.x;
  const int w = t >> 6, l = t & 63, g = l >> 4, lm = l & 15;
  const int wr = w >> 1, wc = w & 1;
  const int sw = (lm & 7) << 3;
  const unsigned short* Wh = WtH + (size_t)mi * 262144;
  const unsigned short* Wl = WtL + (size_t)mi * 262144;
  const float* bias = (mi == 0) ? bq : ((mi == 1) ? bk : bv);

  const f32x4 zf = {0.f, 0.f, 0.f, 0.f};
  f32x4 acc[2][4];
#pragma unroll
  for (int m = 0; m < 2; ++m)
#pragma unroll
    for (int n = 0; n < 4; ++n) acc[m][n] = zf;

  for (int kc = 0; kc < 2048; kc += 64) {
    float4 av[4];
    uint4 bhv[4], blv[4];
#pragma unroll
    for (int i = 0; i < 4; ++i) {
      const int f4 = t + 256 * i;
      const int r_ = f4 >> 4, c4 = (f4 & 15) * 4;
      av[i] = *(const float4*)(x + (size_t)(m0 + r_) * 2048 + kc + c4);
      const int f8 = t + 256 * i;
      const int n_ = f8 >> 3, k8 = (f8 & 7) * 8;
      bhv[i] = *(const uint4*)(Wh + (size_t)n_ * 2048 + kc + k8);
      blv[i] = *(const uint4*)(Wl + (size_t)n_ * 2048 + kc + k8);
    }
    __syncthreads();   // previous iteration's compute done
#pragma unroll
    for (int i = 0; i < 4; ++i) {
      const int f4 = t + 256 * i;
      const int r_ = f4 >> 4, c4 = (f4 & 15) * 4;
      const int ia = r_ * 64 + (c4 ^ ((r_ & 7) << 3));
      ushort4 hh, ll;
      hh.x = bf16_rne(av[i].x); ll.x = bf16_rne(av[i].x - bf16f(hh.x));
      hh.y = bf16_rne(av[i].y); ll.y = bf16_rne(av[i].y - bf16f(hh.y));
      hh.z = bf16_rne(av[i].z); ll.z = bf16_rne(av[i].z - bf16f(hh.z));
      hh.w = bf16_rne(av[i].w); ll.w = bf16_rne(av[i].w - bf16f(hh.w));
      *(ushort4*)&AsH[ia] = hh;
      *(ushort4*)&AsL[ia] = ll;
      const int f8 = t + 256 * i;
      const int n_ = f8 >> 3, k8 = (f8 & 7) * 8;
      const int ib = n_ * 64 + (k8 ^ ((n_ & 7) << 3));
      *(uint4*)&BsH[ib] = bhv[i];
      *(uint4*)&BsL[ib] = blv[i];
    }
    __syncthreads();   // tiles staged
#pragma unroll
    for (int ks = 0; ks < 2; ++ks) {
      const int kb = (ks * 32 + g * 8) ^ sw;
      bf16x8 ah[2], al2[2], bh2[4], bl2[4];
#pragma unroll
      for (int m = 0; m < 2; ++m) {
        const int base = (wr * 32 + m * 16 + lm) * 64 + kb;
        ah[m] = *(const bf16x8*)&AsH[base];
        al2[m] = *(const bf16x8*)&AsL[base];
      }
#pragma unroll
      for (int n = 0; n < 4; ++n) {
        const int base = (wc * 64 + n * 16 + lm) * 64 + kb;
        bh2[n] = *(const bf16x8*)&BsH[base];
        bl2[n] = *(const bf16x8*)&BsL[base];
      }
#pragma unroll
      for (int m = 0; m < 2; ++m)
#pragma unroll
        for (int n = 0; n < 4; ++n) {
          acc[m][n] = MFMA16(ah[m], bh2[n], acc[m][n]);   // hi*hi
          acc[m][n] = MFMA16(ah[m], bl2[n], acc[m][n]);   // hi*lo
          acc[m][n] = MFMA16(al2[m], bh2[n], acc[m][n]);  // lo*hi
        }
    }
  }

  // epilogue: +bias, split hi/lo, store. C frag: row=(l>>4)*4+r, col=l&15.
#pragma unroll
  for (int n = 0; n < 4; ++n) {
    const int col = wc * 64 + n * 16 + lm;
    const float bn = bias[col];
    if (mi < 2) {
      unsigned short* oh = (mi == 0) ? qh : kh;
      unsigned short* ol = (mi == 0) ? ql : kl;
#pragma unroll
      for (int m = 0; m < 2; ++m)
#pragma unroll
        for (int r = 0; r < 4; ++r) {
          const int rowg = m0 + wr * 32 + m * 16 + g * 4 + r;
          const float vv = acc[m][n][r] + bn;
          const unsigned short hh = bf16_rne(vv);
          oh[(size_t)rowg * 128 + col] = hh;
          ol[(size_t)rowg * 128 + col] = bf16_rne(vv - bf16f(hh));
        }
    } else {
#pragma unroll
      for (int m = 0; m < 2; ++m) {
        const int rowg0 = m0 + wr * 32 + m * 16 + g * 4;   // multiple of 4, tile never crosses batch
        const int bidx = rowg0 >> 12;
        const int tb = rowg0 & 4095;
        float v0 = acc[m][n][0] + bn, v1 = acc[m][n][1] + bn;
        float v2 = acc[m][n][2] + bn, v3 = acc[m][n][3] + bn;
        ushort4 hh, ll;
        hh.x = bf16_rne(v0); ll.x = bf16_rne(v0 - bf16f(hh.x));
        hh.y = bf16_rne(v1); ll.y = bf16_rne(v1 - bf16f(hh.y));
        hh.z = bf16_rne(v2); ll.z = bf16_rne(v2 - bf16f(hh.z));
        hh.w = bf16_rne(v3); ll.w = bf16_rne(v3 - bf16f(hh.w));
        const size_t o = (size_t)(bidx * 128 + col) * 4096 + tb;
        *(ushort4*)(vTh + o) = hh;
        *(ushort4*)(vTl + o) = ll;
      }
    }
  }
}

// ---------------------------------------------------------------------------
// attn: flash attention, BQ=64 (4 waves x 16 q-rows), BK=32.
// Block bx -> (pj = bx>>2, s = bx&3); two passes qb = pj then 63-pj, kv tiles
// ti = s, s+4, ... (kv-split-4).  Work/block = 32-33 tiles, constant.
// Swapped QK^T (S^T = K*Q^T) => softmax lane-local + shfl_xor(16,32).
// Split-P (hi/lo) for the PV step.  Partials (unnormalized O, m, l) -> combine.
// ---------------------------------------------------------------------------
__global__ __launch_bounds__(256, 2) void attn(
    const unsigned short* __restrict__ qh, const unsigned short* __restrict__ ql,
    const unsigned short* __restrict__ kh, const unsigned short* __restrict__ kl,
    const unsigned short* __restrict__ vTh, const unsigned short* __restrict__ vTl,
    float* __restrict__ OP, float* __restrict__ ML) {
  __shared__ __align__(16) unsigned short sm[23552];  // 46 KB
  unsigned short* KhL = sm;           // [32][128] XOR-swizzled
  unsigned short* KlL = sm + 4096;
  unsigned short* VhL = sm + 8192;    // [128][40] padded (h-major, kv inner)
  unsigned short* VlL = sm + 13312;
  unsigned short* PhL = sm + 18432;   // [4 waves][16][40] padded
  unsigned short* PlL = sm + 20992;

  const int b = blockIdx.y, bx = blockIdx.x;
  const int pj = bx >> 2, s = bx & 3;
  const int t = threadIdx.x, w = t >> 6, l = t & 63, g = l >> 4, lm = l & 15;
  const int sw = (lm & 7) << 3;
  const size_t bT = (size_t)b * 4096;
  const f32x4 zf = {0.f, 0.f, 0.f, 0.f};

  for (int pass = 0; pass < 2; ++pass) {
    const int qb = pass ? (63 - pj) : pj;         // bijective: qb in 0..31 then 32..63
    const int q0 = qb * 64;
    const int part = b * 256 + qb * 4 + s;

    // Q fragments (hi/lo), all 4 K-steps, in registers for the whole pass
    bf16x8 qfh[4], qfl[4];
    const size_t qoff = (bT + q0 + w * 16 + lm) * 128;
#pragma unroll
    for (int ks = 0; ks < 4; ++ks) {
      qfh[ks] = *(const bf16x8*)(qh + qoff + ks * 32 + g * 8);
      qfl[ks] = *(const bf16x8*)(ql + qoff + ks * 32 + g * 8);
    }

    f32x4 o[8];
#pragma unroll
    for (int n = 0; n < 8; ++n) o[n] = zf;
    float mrow = -1e30f, lrow = 0.f;
    const int qg = q0 + w * 16 + lm;   // this lane's softmax q-row
    const int nt = 2 * qb + 2;

    for (int ti = s; ti < nt; ti += 4) {
      const int t0 = ti * 32;
      // ---- global -> regs (no LDS touch) ----
      uint4 rk0[2], rk1[2], rv0[2], rv1[2];
      int ik[2], iv[2];
#pragma unroll
      for (int i = 0; i < 2; ++i) {
        const int f8 = t + 256 * i;
        const int kr = f8 >> 4, h8 = (f8 & 15) * 8;
        rk0[i] = *(const uint4*)(kh + (bT + t0 + kr) * 128 + h8);
        rk1[i] = *(const uint4*)(kl + (bT + t0 + kr) * 128 + h8);
        ik[i] = kr * 128 + (h8 ^ ((kr & 7) << 3));
        const int hv = f8 >> 2, kv8 = (f8 & 3) * 8;
        rv0[i] = *(const uint4*)(vTh + ((size_t)b * 128 + hv) * 4096 + t0 + kv8);
        rv1[i] = *(const uint4*)(vTl + ((size_t)b * 128 + hv) * 4096 + t0 + kv8);
        iv[i] = hv * 40 + kv8;
      }
      __syncthreads();   // previous tile/pass compute done with LDS
#pragma unroll
      for (int i = 0; i < 2; ++i) {
        *(uint4*)&KhL[ik[i]] = rk0[i];
        *(uint4*)&KlL[ik[i]] = rk1[i];
        *(uint4*)&VhL[iv[i]] = rv0[i];
        *(uint4*)&VlL[iv[i]] = rv1[i];
      }
      __syncthreads();   // K/V staged

      // ---- S^T = K * Q^T (split 3-pass), per wave: [32 kv][16 q] ----
      f32x4 sa[2] = {zf, zf};
#pragma unroll
      for (int ks = 0; ks < 4; ++ks) {
        const int kb = (ks * 32 + g * 8) ^ sw;
#pragma unroll
        for (int m = 0; m < 2; ++m) {
          const bf16x8 kf = *(const bf16x8*)&KhL[(m * 16 + lm) * 128 + kb];
          const bf16x8 lf = *(const bf16x8*)&KlL[(m * 16 + lm) * 128 + kb];
          sa[m] = MFMA16(kf, qfh[ks], sa[m]);
          sa[m] = MFMA16(kf, qfl[ks], sa[m]);
          sa[m] = MFMA16(lf, qfh[ks], sa[m]);
        }
      }

      // ---- online softmax: lane owns column q=qg; kv = t0+16m+4g+r ----
      float pv_[8];
      float mt = -1e30f;
#pragma unroll
      for (int m = 0; m < 2; ++m)
#pragma unroll
        for (int r = 0; r < 4; ++r) {
          const int kvg = t0 + m * 16 + g * 4 + r;
          const float sv = (kvg <= qg) ? sa[m][r] * SM_SCALE : -1e30f;
          pv_[m * 4 + r] = sv;
          mt = fmaxf(mt, sv);
        }
      mt = fmaxf(mt, __shfl_xor(mt, 16));
      mt = fmaxf(mt, __shfl_xor(mt, 32));
      const float mnew = fmaxf(mrow, mt);
      const float sc = __expf(mrow - mnew);       // finite sentinels: never NaN
      float lsum = 0.f;
#pragma unroll
      for (int j = 0; j < 8; ++j) {
        const float pe = (pv_[j] > -9e29f) ? __expf(pv_[j] - mnew) : 0.f;
        pv_[j] = pe;
        lsum += pe;
      }
      lsum += __shfl_xor(lsum, 16);
      lsum += __shfl_xor(lsum, 32);
      lrow = lrow * sc + lsum;
      mrow = mnew;
      // rescale O (lane's O rows are q'=4g+r; sc lives on lane lm'=q')
      float scr[4];
#pragma unroll
      for (int r = 0; r < 4; ++r) scr[r] = __shfl(sc, g * 4 + r);
#pragma unroll
      for (int n = 0; n < 8; ++n)
#pragma unroll
        for (int r = 0; r < 4; ++r) o[n][r] *= scr[r];

      // ---- P -> LDS, SPLIT hi/lo bf16, re-layout for PV A-operand ----
      const int wb = w * 640;
#pragma unroll
      for (int m = 0; m < 2; ++m)
#pragma unroll
        for (int j2 = 0; j2 < 2; ++j2) {
          const int kv0 = m * 16 + g * 4 + j2 * 2;
          const float p0f = pv_[m * 4 + j2 * 2];
          const float p1f = pv_[m * 4 + j2 * 2 + 1];
          ushort2 ph2, pl2;
          ph2.x = bf16_rne(p0f); pl2.x = bf16_rne(p0f - bf16f(ph2.x));
          ph2.y = bf16_rne(p1f); pl2.y = bf16_rne(p1f - bf16f(ph2.y));
          *(ushort2*)&PhL[wb + lm * 40 + kv0] = ph2;
          *(ushort2*)&PlL[wb + lm * 40 + kv0] = pl2;
        }
      // ---- O += Ph*(Vh+Vl) + Pl*Vh (split 3-pass) ----
      const bf16x8 pAh = *(const bf16x8*)&PhL[wb + lm * 40 + g * 8];
      const bf16x8 pAl = *(const bf16x8*)&PlL[wb + lm * 40 + g * 8];
#pragma unroll
      for (int n = 0; n < 8; ++n) {
        const bf16x8 vf = *(const bf16x8*)&VhL[(n * 16 + lm) * 40 + g * 8];
        const bf16x8 wf = *(const bf16x8*)&VlL[(n * 16 + lm) * 40 + g * 8];
        o[n] = MFMA16(pAh, vf, o[n]);
        o[n] = MFMA16(pAh, wf, o[n]);
        o[n] = MFMA16(pAl, vf, o[n]);
      }
    } // kv tiles

    // ---- store partials (every part written exactly once) ----
    float* OPp = OP + (size_t)part * 8192;
#pragma unroll
    for (int n = 0; n < 8; ++n)
#pragma unroll
      for (int r = 0; r < 4; ++r)
        OPp[(size_t)(w * 16 + g * 4 + r) * 128 + n * 16 + lm] = o[n][r];
    if (l < 16) {
      ML[((size_t)part * 64 + w * 16 + l) * 2 + 0] = mrow;
      ML[((size_t)part * 64 + w * 16 + l) * 2 + 1] = lrow;
    }
  } // pass
}

// ---------------------------------------------------------------------------
// combine: merge the 4 kv-split partials per q-row. 256 blocks x 256 thr.
// ---------------------------------------------------------------------------
__global__ void combine(const float* __restrict__ OP, const float* __restrict__ ML,
                        float* __restrict__ out) {
  const int x = blockIdx.x;
  const int b = x >> 6, qb = x & 63;
  const int p0 = b * 256 + qb * 4;
  const int t = threadIdx.x;
  const int r = t >> 2, hq = (t & 3) * 32;
  float m[4], ll[4];
#pragma unroll
  for (int s2 = 0; s2 < 4; ++s2) {
    m[s2]  = ML[((size_t)(p0 + s2) * 64 + r) * 2 + 0];
    ll[s2] = ML[((size_t)(p0 + s2) * 64 + r) * 2 + 1];
  }
  const float mx = fmaxf(fmaxf(m[0], m[1]), fmaxf(m[2], m[3]));  // split 0 always real
  float wgt[4], den = 0.f;
#pragma unroll
  for (int s2 = 0; s2 < 4; ++s2) {
    wgt[s2] = __expf(m[s2] - mx);   // empty split: exp(-huge)=0
    den += wgt[s2] * ll[s2];
  }
  const float inv = 1.f / den;
  float* op = out + ((size_t)(b * 4096 + qb * 64 + r)) * 128 + hq;
#pragma unroll
  for (int j = 0; j < 8; ++j) {
    float ax = 0.f, ay = 0.f, az = 0.f, aw = 0.f;
#pragma unroll
    for (int s2 = 0; s2 < 4; ++s2) {
      const float4 pv = *(const float4*)(OP + ((size_t)(p0 + s2) * 64 + r) * 128 + hq + j * 4);
      ax += wgt[s2] * pv.x; ay += wgt[s2] * pv.y;
      az += wgt[s2] * pv.z; aw += wgt[s2] * pv.w;
    }
    float4 ov; ov.x = ax * inv; ov.y = ay * inv; ov.z = az * inv; ov.w = aw * inv;
    *(float4*)(op + j * 4) = ov;
  }
}

}  // namespace

extern "C" void kernel_launch(void* const* d_in, const int* in_sizes, int n_in,
                              void* d_out, int out_size, void* d_ws, size_t ws_size,
                              hipStream_t stream) {
  // setup_inputs order: x, Wk, bk, Wq, bq, Wv, bv
  const float* x  = (const float*)d_in[0];
  const float* Wk = (const float*)d_in[1];
  const float* bk = (const float*)d_in[2];
  const float* Wq = (const float*)d_in[3];
  const float* bq = (const float*)d_in[4];
  const float* Wv = (const float*)d_in[5];
  const float* bv = (const float*)d_in[6];
  float* out = (float*)d_out;

  // workspace carve (~59.5 MB)
  unsigned short* WtH = (unsigned short*)d_ws;           // 3*128*2048
  unsigned short* WtL = WtH + 786432;
  unsigned short* qh  = WtL + 786432;                    // [16384][128] each
  unsigned short* ql  = qh + 2097152;
  unsigned short* kh  = ql + 2097152;
  unsigned short* kl  = kh + 2097152;
  unsigned short* vTh = kl + 2097152;                    // [4][128][4096]
  unsigned short* vTl = vTh + 2097152;
  float* OP = (float*)(vTl + 2097152);                   // [1024][64][128]
  float* ML = OP + (size_t)1024 * 8192;                  // [1024][64][2]

  prep_w<<<384, 256, 0, stream>>>(Wq, Wk, Wv, WtH, WtL);
  qkv_gemm<<<dim3(3, 256), 256, 0, stream>>>(x, WtH, WtL, bq, bk, bv,
                                             qh, ql, kh, kl, vTh, vTl);
  attn<<<dim3(128, 4), 256, 0, stream>>>(qh, ql, kh, kl, vTh, vTl, OP, ML);
  combine<<<256, 256, 0, stream>>>(OP, ML, out);
}

// Round 4
// 531.680 us; speedup vs baseline: 1.2955x; 1.2955x over previous
//
#include <hip/hip_runtime.h>

namespace {

typedef float f32x4 __attribute__((ext_vector_type(4)));
typedef short bf16x8 __attribute__((ext_vector_type(8)));

constexpr float SM_SCALE = 0.08838834764831845f; // 1/sqrt(128)

#define MFMA16(a, b, c) __builtin_amdgcn_mfma_f32_16x16x32_bf16((a), (b), (c), 0, 0, 0)

__device__ __forceinline__ unsigned short bf16_rne(float x) {
  unsigned u = __float_as_uint(x);
  u += 0x7fffu + ((u >> 16) & 1u);
  return (unsigned short)(u >> 16);
}
__device__ __forceinline__ float bf16f(unsigned short h) {
  return __uint_as_float(((unsigned)h) << 16);
}
__device__ __forceinline__ void gld16(const void* g, void* l) {
  __builtin_amdgcn_global_load_lds(
      (const __attribute__((address_space(1))) unsigned int*)g,
      (__attribute__((address_space(3))) unsigned int*)l, 16, 0, 0);
}

// ---------------------------------------------------------------------------
// prep_w: W[2048][128] fp32 -> Wt_hi/Wt_lo [3][128][2048] bf16 (transposed).
// ---------------------------------------------------------------------------
__global__ void prep_w(const float* __restrict__ Wq, const float* __restrict__ Wk,
                       const float* __restrict__ Wv,
                       unsigned short* __restrict__ WtH, unsigned short* __restrict__ WtL) {
  const int tg = blockIdx.x * 256 + threadIdx.x;   // 0..98303
  const int mi = tg >> 15;                          // 0=q 1=k 2=v
  const int rem = tg & 32767;
  const int n = rem & 127;
  const int k0 = (rem >> 7) * 8;
  const float* W = (mi == 0) ? Wq : ((mi == 1) ? Wk : Wv);
  unsigned hv[8], lv[8];
#pragma unroll
  for (int e = 0; e < 8; ++e) {
    float xx = W[(size_t)(k0 + e) * 128 + n];
    unsigned short hh = bf16_rne(xx);
    hv[e] = hh;
    lv[e] = bf16_rne(xx - bf16f(hh));
  }
  uint4 uh, ul;
  uh.x = hv[0] | (hv[1] << 16); uh.y = hv[2] | (hv[3] << 16);
  uh.z = hv[4] | (hv[5] << 16); uh.w = hv[6] | (hv[7] << 16);
  ul.x = lv[0] | (lv[1] << 16); ul.y = lv[2] | (lv[3] << 16);
  ul.z = lv[4] | (lv[5] << 16); ul.w = lv[6] | (lv[7] << 16);
  const size_t off = (size_t)mi * 262144 + (size_t)n * 2048 + k0;
  *(uint4*)(WtH + off) = uh;
  *(uint4*)(WtL + off) = ul;
}

// ---------------------------------------------------------------------------
// qkv_gemm v3: out[M,128] = x[M,2048] @ W + b, split-bf16 3-pass MFMA.
// grid (3, 128), 256 thr = 4 waves (2x2), BM=128 BN=128 BK=64.
// B staged via global_load_lds (16B) with pre-swizzled global source;
// A staged reg->convert->LDS with next-chunk prefetch under MFMA shadow.
// ---------------------------------------------------------------------------
__global__ __launch_bounds__(256, 2) void qkv_gemm(
    const float* __restrict__ x,
    const unsigned short* __restrict__ WtH, const unsigned short* __restrict__ WtL,
    const float* __restrict__ bq, const float* __restrict__ bk, const float* __restrict__ bv,
    unsigned short* __restrict__ qh, unsigned short* __restrict__ ql,
    unsigned short* __restrict__ kh, unsigned short* __restrict__ kl,
    unsigned short* __restrict__ vTh, unsigned short* __restrict__ vTl) {
  __shared__ __align__(16) unsigned short sm[32768];   // 64 KB
  unsigned short* AsH = sm;            // [128][64] swizzled
  unsigned short* AsL = sm + 8192;
  unsigned short* BsH = sm + 16384;    // [128][64] n-major, swizzled
  unsigned short* BsL = sm + 24576;

  const int mi = blockIdx.x;
  const int m0 = blockIdx.y * 128;
  const int t = threadIdx.x;
  const int w = t >> 6, l = t & 63, g = l >> 4, lm = l & 15;
  const int wr = w >> 1, wc = w & 1;
  const int sw = (lm & 7) << 3;
  const unsigned short* WhP = WtH + (size_t)mi * 262144;
  const unsigned short* WlP = WtL + (size_t)mi * 262144;
  const float* bias = (mi == 0) ? bq : ((mi == 1) ? bk : bv);

  // A-load map: instr i covers rows i*16+(t>>4), cols (t&15)*4 (fully coalesced)
  const int arow = t >> 4, ac4 = (t & 15) * 4;
  // B gload map (per wave-instr): lane ln covers n = blk*8 + (ln>>3), kk0=(ln&7)*8
  const int ln = l;
  const int nsub = ln >> 3, kk0 = (ln & 7) * 8;

  const f32x4 zf = {0.f, 0.f, 0.f, 0.f};
  f32x4 acc[4][4];
#pragma unroll
  for (int m = 0; m < 4; ++m)
#pragma unroll
    for (int n = 0; n < 4; ++n) acc[m][n] = zf;

  // prologue: preload A chunk 0
  float4 av[8];
#pragma unroll
  for (int i = 0; i < 8; ++i)
    av[i] = *(const float4*)(x + (size_t)(m0 + i * 16 + arow) * 2048 + 0 + ac4);

  for (int kc = 0; kc < 2048; kc += 64) {
    __syncthreads();   // all waves done reading LDS (previous chunk)
    // ---- B: async DMA global -> LDS (pre-swizzled source, linear dest) ----
#pragma unroll
    for (int i = 0; i < 4; ++i) {
      const int blk = w * 4 + i;              // 1KB block index 0..15
      const int n = blk * 8 + nsub;
      const size_t go = (size_t)n * 2048 + kc + (kk0 ^ ((n & 7) << 3));
      gld16(WhP + go, BsH + blk * 512);
      gld16(WlP + go, BsL + blk * 512);
    }
    // ---- A: convert prefetched fp32 -> hi/lo, write swizzled ----
#pragma unroll
    for (int i = 0; i < 8; ++i) {
      const int row = i * 16 + arow;
      const int idx = row * 64 + (ac4 ^ ((row & 7) << 3));
      ushort4 hh, ll;
      hh.x = bf16_rne(av[i].x); ll.x = bf16_rne(av[i].x - bf16f(hh.x));
      hh.y = bf16_rne(av[i].y); ll.y = bf16_rne(av[i].y - bf16f(hh.y));
      hh.z = bf16_rne(av[i].z); ll.z = bf16_rne(av[i].z - bf16f(hh.z));
      hh.w = bf16_rne(av[i].w); ll.w = bf16_rne(av[i].w - bf16f(hh.w));
      *(ushort4*)&AsH[idx] = hh;
      *(ushort4*)&AsL[idx] = ll;
    }
    __syncthreads();   // B DMA drained (vmcnt0 before barrier) + A staged

    // ---- prefetch next A chunk (hides under MFMA) ----
    if (kc + 64 < 2048) {
#pragma unroll
      for (int i = 0; i < 8; ++i)
        av[i] = *(const float4*)(x + (size_t)(m0 + i * 16 + arow) * 2048 + kc + 64 + ac4);
    }

    // ---- MFMA inner ----
#pragma unroll
    for (int ks = 0; ks < 2; ++ks) {
      const int kb = ks * 32 + g * 8;
      bf16x8 ah[4], al_[4], bh_[4], bl_[4];
#pragma unroll
      for (int m = 0; m < 4; ++m) {
        const int row = wr * 64 + m * 16 + lm;
        const int idx = row * 64 + (kb ^ sw);
        ah[m] = *(const bf16x8*)&AsH[idx];
        al_[m] = *(const bf16x8*)&AsL[idx];
      }
#pragma unroll
      for (int n = 0; n < 4; ++n) {
        const int row = wc * 64 + n * 16 + lm;
        const int idx = row * 64 + (kb ^ sw);
        bh_[n] = *(const bf16x8*)&BsH[idx];
        bl_[n] = *(const bf16x8*)&BsL[idx];
      }
#pragma unroll
      for (int m = 0; m < 4; ++m)
#pragma unroll
        for (int n = 0; n < 4; ++n) {
          acc[m][n] = MFMA16(ah[m], bh_[n], acc[m][n]);   // hi*hi
          acc[m][n] = MFMA16(ah[m], bl_[n], acc[m][n]);   // hi*lo
          acc[m][n] = MFMA16(al_[m], bh_[n], acc[m][n]);  // lo*hi
        }
    }
  }

  // epilogue: +bias, split hi/lo, store. C frag: row=g*4+r (+16*m), col=lm (+16*n).
#pragma unroll
  for (int n = 0; n < 4; ++n) {
    const int col = wc * 64 + n * 16 + lm;
    const float bn = bias[col];
    if (mi < 2) {
      unsigned short* oh = (mi == 0) ? qh : kh;
      unsigned short* ol = (mi == 0) ? ql : kl;
#pragma unroll
      for (int m = 0; m < 4; ++m)
#pragma unroll
        for (int r = 0; r < 4; ++r) {
          const int rowg = m0 + wr * 64 + m * 16 + g * 4 + r;
          const float vv = acc[m][n][r] + bn;
          const unsigned short hh = bf16_rne(vv);
          oh[(size_t)rowg * 128 + col] = hh;
          ol[(size_t)rowg * 128 + col] = bf16_rne(vv - bf16f(hh));
        }
    } else {
#pragma unroll
      for (int m = 0; m < 4; ++m) {
        const int rowg0 = m0 + wr * 64 + m * 16 + g * 4;   // 4-aligned; tile within one batch
        const int bidx = rowg0 >> 12;
        const int tb = rowg0 & 4095;
        float v0 = acc[m][n][0] + bn, v1 = acc[m][n][1] + bn;
        float v2 = acc[m][n][2] + bn, v3 = acc[m][n][3] + bn;
        ushort4 hh, ll;
        hh.x = bf16_rne(v0); ll.x = bf16_rne(v0 - bf16f(hh.x));
        hh.y = bf16_rne(v1); ll.y = bf16_rne(v1 - bf16f(hh.y));
        hh.z = bf16_rne(v2); ll.z = bf16_rne(v2 - bf16f(hh.z));
        hh.w = bf16_rne(v3); ll.w = bf16_rne(v3 - bf16f(hh.w));
        const size_t o = (size_t)(bidx * 128 + col) * 4096 + tb;
        *(ushort4*)(vTh + o) = hh;
        *(ushort4*)(vTl + o) = ll;
      }
    }
  }
}

// ---------------------------------------------------------------------------
// attn: flash attention, BQ=64 (4 waves x 16 q-rows), BK=32, kv-split-4.
// Block bx -> (pj, s); passes qb = pj then 63-pj. T14 issue-early prefetch:
// next tile's K/V global loads issued before current tile's compute.
// ---------------------------------------------------------------------------
__global__ __launch_bounds__(256, 2) void attn(
    const unsigned short* __restrict__ qh, const unsigned short* __restrict__ ql,
    const unsigned short* __restrict__ kh, const unsigned short* __restrict__ kl,
    const unsigned short* __restrict__ vTh, const unsigned short* __restrict__ vTl,
    float* __restrict__ OP, float* __restrict__ ML) {
  __shared__ __align__(16) unsigned short sm[23552];  // 46 KB
  unsigned short* KhL = sm;           // [32][128] XOR-swizzled
  unsigned short* KlL = sm + 4096;
  unsigned short* VhL = sm + 8192;    // [128][40] padded (h-major, kv inner)
  unsigned short* VlL = sm + 13312;
  unsigned short* PhL = sm + 18432;   // [4 waves][16][40] padded
  unsigned short* PlL = sm + 20992;

  const int b = blockIdx.y, bx = blockIdx.x;
  const int pj = bx >> 2, s = bx & 3;
  const int t = threadIdx.x, w = t >> 6, l = t & 63, g = l >> 4, lm = l & 15;
  const int sw = (lm & 7) << 3;
  const size_t bT = (size_t)b * 4096;
  const f32x4 zf = {0.f, 0.f, 0.f, 0.f};

  // hoisted per-thread staging maps (t0-independent parts)
  int ikc[2], ivc[2];
  size_t kgo[2], vgo[2];
#pragma unroll
  for (int i = 0; i < 2; ++i) {
    const int f8 = t + 256 * i;
    const int kr = f8 >> 4, h8 = (f8 & 15) * 8;
    ikc[i] = kr * 128 + (h8 ^ ((kr & 7) << 3));
    kgo[i] = (size_t)kr * 128 + h8;
    const int hv = f8 >> 2, kv8 = (f8 & 3) * 8;
    ivc[i] = hv * 40 + kv8;
    vgo[i] = ((size_t)b * 128 + hv) * 4096 + kv8;
  }

  for (int pass = 0; pass < 2; ++pass) {
    const int qb = pass ? (63 - pj) : pj;
    const int q0 = qb * 64;
    const int part = b * 256 + qb * 4 + s;

    bf16x8 qfh[4], qfl[4];
    const size_t qoff = (bT + q0 + w * 16 + lm) * 128;
#pragma unroll
    for (int ks = 0; ks < 4; ++ks) {
      qfh[ks] = *(const bf16x8*)(qh + qoff + ks * 32 + g * 8);
      qfl[ks] = *(const bf16x8*)(ql + qoff + ks * 32 + g * 8);
    }

    f32x4 o[8];
#pragma unroll
    for (int n = 0; n < 8; ++n) o[n] = zf;
    float mrow = -1e30f, lrow = 0.f;
    const int qg = q0 + w * 16 + lm;
    const int nt = 2 * qb + 2;

    // prologue preload (harmless in-bounds read even if loop runs zero times)
    uint4 rk0[2], rk1[2], rv0[2], rv1[2];
    {
      const size_t kb0 = (bT + s * 32) * 128;
#pragma unroll
      for (int i = 0; i < 2; ++i) {
        rk0[i] = *(const uint4*)(kh + kb0 + kgo[i]);
        rk1[i] = *(const uint4*)(kl + kb0 + kgo[i]);
        rv0[i] = *(const uint4*)(vTh + vgo[i] + s * 32);
        rv1[i] = *(const uint4*)(vTl + vgo[i] + s * 32);
      }
    }

    for (int ti = s; ti < nt; ti += 4) {
      const int t0 = ti * 32;
      __syncthreads();   // previous tile/pass compute done with LDS
#pragma unroll
      for (int i = 0; i < 2; ++i) {
        *(uint4*)&KhL[ikc[i]] = rk0[i];
        *(uint4*)&KlL[ikc[i]] = rk1[i];
        *(uint4*)&VhL[ivc[i]] = rv0[i];
        *(uint4*)&VlL[ivc[i]] = rv1[i];
      }
      __syncthreads();   // K/V staged

      // ---- issue NEXT tile's loads now (latency hides under compute) ----
      if (ti + 4 < nt) {
        const size_t kb1 = (bT + (t0 + 128)) * 128;
#pragma unroll
        for (int i = 0; i < 2; ++i) {
          rk0[i] = *(const uint4*)(kh + kb1 + kgo[i]);
          rk1[i] = *(const uint4*)(kl + kb1 + kgo[i]);
          rv0[i] = *(const uint4*)(vTh + vgo[i] + t0 + 128);
          rv1[i] = *(const uint4*)(vTl + vgo[i] + t0 + 128);
        }
      }

      // ---- S^T = K * Q^T (split 3-pass), per wave: [32 kv][16 q] ----
      f32x4 sa[2] = {zf, zf};
#pragma unroll
      for (int ks = 0; ks < 4; ++ks) {
        const int kb = (ks * 32 + g * 8) ^ sw;
#pragma unroll
        for (int m = 0; m < 2; ++m) {
          const bf16x8 kf = *(const bf16x8*)&KhL[(m * 16 + lm) * 128 + kb];
          const bf16x8 lf = *(const bf16x8*)&KlL[(m * 16 + lm) * 128 + kb];
          sa[m] = MFMA16(kf, qfh[ks], sa[m]);
          sa[m] = MFMA16(kf, qfl[ks], sa[m]);
          sa[m] = MFMA16(lf, qfh[ks], sa[m]);
        }
      }

      // ---- online softmax (lane owns q-row qg; kv = t0+16m+4g+r) ----
      float pv_[8];
      float mt = -1e30f;
#pragma unroll
      for (int m = 0; m < 2; ++m)
#pragma unroll
        for (int r = 0; r < 4; ++r) {
          const int kvg = t0 + m * 16 + g * 4 + r;
          const float sv = (kvg <= qg) ? sa[m][r] * SM_SCALE : -1e30f;
          pv_[m * 4 + r] = sv;
          mt = fmaxf(mt, sv);
        }
      mt = fmaxf(mt, __shfl_xor(mt, 16));
      mt = fmaxf(mt, __shfl_xor(mt, 32));
      const float mnew = fmaxf(mrow, mt);
      const float sc = __expf(mrow - mnew);
      float lsum = 0.f;
#pragma unroll
      for (int j = 0; j < 8; ++j) {
        const float pe = (pv_[j] > -9e29f) ? __expf(pv_[j] - mnew) : 0.f;
        pv_[j] = pe;
        lsum += pe;
      }
      lsum += __shfl_xor(lsum, 16);
      lsum += __shfl_xor(lsum, 32);
      lrow = lrow * sc + lsum;
      mrow = mnew;
      float scr[4];
#pragma unroll
      for (int r = 0; r < 4; ++r) scr[r] = __shfl(sc, g * 4 + r);
#pragma unroll
      for (int n = 0; n < 8; ++n)
#pragma unroll
        for (int r = 0; r < 4; ++r) o[n][r] *= scr[r];

      // ---- P -> LDS, split hi/lo bf16 ----
      const int wb = w * 640;
#pragma unroll
      for (int m = 0; m < 2; ++m)
#pragma unroll
        for (int j2 = 0; j2 < 2; ++j2) {
          const int kv0 = m * 16 + g * 4 + j2 * 2;
          const float p0f = pv_[m * 4 + j2 * 2];
          const float p1f = pv_[m * 4 + j2 * 2 + 1];
          ushort2 ph2, pl2;
          ph2.x = bf16_rne(p0f); pl2.x = bf16_rne(p0f - bf16f(ph2.x));
          ph2.y = bf16_rne(p1f); pl2.y = bf16_rne(p1f - bf16f(ph2.y));
          *(ushort2*)&PhL[wb + lm * 40 + kv0] = ph2;
          *(ushort2*)&PlL[wb + lm * 40 + kv0] = pl2;
        }
      // ---- O += Ph*(Vh+Vl) + Pl*Vh ----
      const bf16x8 pAh = *(const bf16x8*)&PhL[wb + lm * 40 + g * 8];
      const bf16x8 pAl = *(const bf16x8*)&PlL[wb + lm * 40 + g * 8];
#pragma unroll
      for (int n = 0; n < 8; ++n) {
        const bf16x8 vf = *(const bf16x8*)&VhL[(n * 16 + lm) * 40 + g * 8];
        const bf16x8 wf = *(const bf16x8*)&VlL[(n * 16 + lm) * 40 + g * 8];
        o[n] = MFMA16(pAh, vf, o[n]);
        o[n] = MFMA16(pAh, wf, o[n]);
        o[n] = MFMA16(pAl, vf, o[n]);
      }
    } // kv tiles

    float* OPp = OP + (size_t)part * 8192;
#pragma unroll
    for (int n = 0; n < 8; ++n)
#pragma unroll
      for (int r = 0; r < 4; ++r)
        OPp[(size_t)(w * 16 + g * 4 + r) * 128 + n * 16 + lm] = o[n][r];
    if (l < 16) {
      ML[((size_t)part * 64 + w * 16 + l) * 2 + 0] = mrow;
      ML[((size_t)part * 64 + w * 16 + l) * 2 + 1] = lrow;
    }
  } // pass
}

// ---------------------------------------------------------------------------
// combine: merge the 4 kv-split partials per q-row. 256 blocks x 256 thr.
// ---------------------------------------------------------------------------
__global__ void combine(const float* __restrict__ OP, const float* __restrict__ ML,
                        float* __restrict__ out) {
  const int x = blockIdx.x;
  const int b = x >> 6, qb = x & 63;
  const int p0 = b * 256 + qb * 4;
  const int t = threadIdx.x;
  const int r = t >> 2, hq = (t & 3) * 32;
  float m[4], ll[4];
#pragma unroll
  for (int s2 = 0; s2 < 4; ++s2) {
    m[s2]  = ML[((size_t)(p0 + s2) * 64 + r) * 2 + 0];
    ll[s2] = ML[((size_t)(p0 + s2) * 64 + r) * 2 + 1];
  }
  const float mx = fmaxf(fmaxf(m[0], m[1]), fmaxf(m[2], m[3]));
  float wgt[4], den = 0.f;
#pragma unroll
  for (int s2 = 0; s2 < 4; ++s2) {
    wgt[s2] = __expf(m[s2] - mx);
    den += wgt[s2] * ll[s2];
  }
  const float inv = 1.f / den;
  float* op = out + ((size_t)(b * 4096 + qb * 64 + r)) * 128 + hq;
#pragma unroll
  for (int j = 0; j < 8; ++j) {
    float ax = 0.f, ay = 0.f, az = 0.f, aw = 0.f;
#pragma unroll
    for (int s2 = 0; s2 < 4; ++s2) {
      const float4 pv = *(const float4*)(OP + ((size_t)(p0 + s2) * 64 + r) * 128 + hq + j * 4);
      ax += wgt[s2] * pv.x; ay += wgt[s2] * pv.y;
      az += wgt[s2] * pv.z; aw += wgt[s2] * pv.w;
    }
    float4 ov; ov.x = ax * inv; ov.y = ay * inv; ov.z = az * inv; ov.w = aw * inv;
    *(float4*)(op + j * 4) = ov;
  }
}

}  // namespace

extern "C" void kernel_launch(void* const* d_in, const int* in_sizes, int n_in,
                              void* d_out, int out_size, void* d_ws, size_t ws_size,
                              hipStream_t stream) {
  // setup_inputs order: x, Wk, bk, Wq, bq, Wv, bv
  const float* x  = (const float*)d_in[0];
  const float* Wk = (const float*)d_in[1];
  const float* bk = (const float*)d_in[2];
  const float* Wq = (const float*)d_in[3];
  const float* bq = (const float*)d_in[4];
  const float* Wv = (const float*)d_in[5];
  const float* bv = (const float*)d_in[6];
  float* out = (float*)d_out;

  // workspace carve (~59.5 MB)
  unsigned short* WtH = (unsigned short*)d_ws;           // 3*128*2048
  unsigned short* WtL = WtH + 786432;
  unsigned short* qh  = WtL + 786432;                    // [16384][128] each
  unsigned short* ql  = qh + 2097152;
  unsigned short* kh  = ql + 2097152;
  unsigned short* kl  = kh + 2097152;
  unsigned short* vTh = kl + 2097152;                    // [4][128][4096]
  unsigned short* vTl = vTh + 2097152;
  float* OP = (float*)(vTl + 2097152);                   // [1024][64][128]
  float* ML = OP + (size_t)1024 * 8192;                  // [1024][64][2]

  prep_w<<<384, 256, 0, stream>>>(Wq, Wk, Wv, WtH, WtL);
  qkv_gemm<<<dim3(3, 128), 256, 0, stream>>>(x, WtH, WtL, bq, bk, bv,
                                             qh, ql, kh, kl, vTh, vTl);
  attn<<<dim3(128, 4), 256, 0, stream>>>(qh, ql, kh, kl, vTh, vTl, OP, ML);
  combine<<<256, 256, 0, stream>>>(OP, ML, out);
}

// Round 5
// 380.668 us; speedup vs baseline: 1.8094x; 1.3967x over previous
//
#include <hip/hip_runtime.h>

namespace {

typedef float f32x4 __attribute__((ext_vector_type(4)));
typedef short bf16x8 __attribute__((ext_vector_type(8)));

constexpr float SM_SCALE = 0.08838834764831845f; // 1/sqrt(128)

#define MFMA16(a, b, c) __builtin_amdgcn_mfma_f32_16x16x32_bf16((a), (b), (c), 0, 0, 0)

__device__ __forceinline__ unsigned short bf16_rne(float x) {
  unsigned u = __float_as_uint(x);
  u += 0x7fffu + ((u >> 16) & 1u);
  return (unsigned short)(u >> 16);
}
__device__ __forceinline__ float bf16f(unsigned short h) {
  return __uint_as_float(((unsigned)h) << 16);
}
__device__ __forceinline__ void gld16(const void* g, void* l) {
  __builtin_amdgcn_global_load_lds(
      (const __attribute__((address_space(1))) unsigned int*)g,
      (__attribute__((address_space(3))) unsigned int*)l, 16, 0, 0);
}
__device__ __forceinline__ uint4 pack8(const unsigned short* h) {
  uint4 u;
  u.x = (unsigned)h[0] | ((unsigned)h[1] << 16);
  u.y = (unsigned)h[2] | ((unsigned)h[3] << 16);
  u.z = (unsigned)h[4] | ((unsigned)h[5] << 16);
  u.w = (unsigned)h[6] | ((unsigned)h[7] << 16);
  return u;
}

// ---------------------------------------------------------------------------
// prep_w: W[2048][128] fp32 -> Wt_hi/Wt_lo [3][128][2048] bf16 (transposed).
// ---------------------------------------------------------------------------
__global__ void prep_w(const float* __restrict__ Wq, const float* __restrict__ Wk,
                       const float* __restrict__ Wv,
                       unsigned short* __restrict__ WtH, unsigned short* __restrict__ WtL) {
  const int tg = blockIdx.x * 256 + threadIdx.x;   // 0..98303
  const int mi = tg >> 15;                          // 0=q 1=k 2=v
  const int rem = tg & 32767;
  const int n = rem & 127;
  const int k0 = (rem >> 7) * 8;
  const float* W = (mi == 0) ? Wq : ((mi == 1) ? Wk : Wv);
  unsigned short hv[8], lv[8];
#pragma unroll
  for (int e = 0; e < 8; ++e) {
    float xx = W[(size_t)(k0 + e) * 128 + n];
    unsigned short hh = bf16_rne(xx);
    hv[e] = hh;
    lv[e] = bf16_rne(xx - bf16f(hh));
  }
  const size_t off = (size_t)mi * 262144 + (size_t)n * 2048 + k0;
  *(uint4*)(WtH + off) = pack8(hv);
  *(uint4*)(WtL + off) = pack8(lv);
}

// ---------------------------------------------------------------------------
// qkv_gemm: out[M,128] = x[M,2048] @ W + b, split-bf16 3-pass MFMA.
// grid (3, 128), 256 thr = 4 waves (2x2), BM=128 BN=128 BK=64.
// B via global_load_lds; A fp32->hi/lo convert with prefetch; epilogue
// through-LDS for fully-coalesced 16B stores (q/k planes and transposed vT).
// ---------------------------------------------------------------------------
__global__ __launch_bounds__(256, 2) void qkv_gemm(
    const float* __restrict__ x,
    const unsigned short* __restrict__ WtH, const unsigned short* __restrict__ WtL,
    const float* __restrict__ bq, const float* __restrict__ bk, const float* __restrict__ bv,
    unsigned short* __restrict__ qh, unsigned short* __restrict__ ql,
    unsigned short* __restrict__ kh, unsigned short* __restrict__ kl,
    unsigned short* __restrict__ vTh, unsigned short* __restrict__ vTl) {
  __shared__ __align__(16) unsigned short sm[32768];   // 64 KB
  unsigned short* AsH = sm;            // [128][64] swizzled
  unsigned short* AsL = sm + 8192;
  unsigned short* BsH = sm + 16384;    // [128][64] n-major, swizzled
  unsigned short* BsL = sm + 24576;

  const int mi = blockIdx.x;
  const int m0 = blockIdx.y * 128;
  const int t = threadIdx.x;
  const int w = t >> 6, l = t & 63, g = l >> 4, lm = l & 15;
  const int wr = w >> 1, wc = w & 1;
  const int sw = (lm & 7) << 3;
  const unsigned short* WhP = WtH + (size_t)mi * 262144;
  const unsigned short* WlP = WtL + (size_t)mi * 262144;
  const float* bias = (mi == 0) ? bq : ((mi == 1) ? bk : bv);

  const int arow = t >> 4, ac4 = (t & 15) * 4;
  const int nsub = l >> 3, kk0 = (l & 7) * 8;

  const f32x4 zf = {0.f, 0.f, 0.f, 0.f};
  f32x4 acc[4][4];
#pragma unroll
  for (int m = 0; m < 4; ++m)
#pragma unroll
    for (int n = 0; n < 4; ++n) acc[m][n] = zf;

  float4 av[8];
#pragma unroll
  for (int i = 0; i < 8; ++i)
    av[i] = *(const float4*)(x + (size_t)(m0 + i * 16 + arow) * 2048 + ac4);

  for (int kc = 0; kc < 2048; kc += 64) {
    __syncthreads();
#pragma unroll
    for (int i = 0; i < 4; ++i) {
      const int blk = w * 4 + i;              // 1KB block 0..15
      const int n = blk * 8 + nsub;
      const size_t go = (size_t)n * 2048 + kc + (kk0 ^ ((n & 7) << 3));
      gld16(WhP + go, BsH + blk * 512);
      gld16(WlP + go, BsL + blk * 512);
    }
#pragma unroll
    for (int i = 0; i < 8; ++i) {
      const int row = i * 16 + arow;
      const int idx = row * 64 + (ac4 ^ ((row & 7) << 3));
      ushort4 hh, ll;
      hh.x = bf16_rne(av[i].x); ll.x = bf16_rne(av[i].x - bf16f(hh.x));
      hh.y = bf16_rne(av[i].y); ll.y = bf16_rne(av[i].y - bf16f(hh.y));
      hh.z = bf16_rne(av[i].z); ll.z = bf16_rne(av[i].z - bf16f(hh.z));
      hh.w = bf16_rne(av[i].w); ll.w = bf16_rne(av[i].w - bf16f(hh.w));
      *(ushort4*)&AsH[idx] = hh;
      *(ushort4*)&AsL[idx] = ll;
    }
    __syncthreads();

    if (kc + 64 < 2048) {
#pragma unroll
      for (int i = 0; i < 8; ++i)
        av[i] = *(const float4*)(x + (size_t)(m0 + i * 16 + arow) * 2048 + kc + 64 + ac4);
    }

    __builtin_amdgcn_s_setprio(1);
#pragma unroll
    for (int ks = 0; ks < 2; ++ks) {
      const int kb = ks * 32 + g * 8;
      bf16x8 ah[4], al_[4], bh_[4], bl_[4];
#pragma unroll
      for (int m = 0; m < 4; ++m) {
        const int row = wr * 64 + m * 16 + lm;
        const int idx = row * 64 + (kb ^ sw);
        ah[m] = *(const bf16x8*)&AsH[idx];
        al_[m] = *(const bf16x8*)&AsL[idx];
      }
#pragma unroll
      for (int n = 0; n < 4; ++n) {
        const int row = wc * 64 + n * 16 + lm;
        const int idx = row * 64 + (kb ^ sw);
        bh_[n] = *(const bf16x8*)&BsH[idx];
        bl_[n] = *(const bf16x8*)&BsL[idx];
      }
#pragma unroll
      for (int m = 0; m < 4; ++m)
#pragma unroll
        for (int n = 0; n < 4; ++n) {
          acc[m][n] = MFMA16(ah[m], bh_[n], acc[m][n]);
          acc[m][n] = MFMA16(ah[m], bl_[n], acc[m][n]);
          acc[m][n] = MFMA16(al_[m], bh_[n], acc[m][n]);
        }
    }
    __builtin_amdgcn_s_setprio(0);
  }

  // ---- epilogue: dump C to LDS (fp32), then coalesced 16B stores ----
  __syncthreads();
  float* Cb = (float*)sm;   // [128][128]
#pragma unroll
  for (int n = 0; n < 4; ++n) {
    const int col = wc * 64 + n * 16 + lm;
    const float bn = bias[col];
#pragma unroll
    for (int m = 0; m < 4; ++m)
#pragma unroll
      for (int r = 0; r < 4; ++r)
        Cb[(wr * 64 + m * 16 + g * 4 + r) * 128 + col] = acc[m][n][r] + bn;
  }
  __syncthreads();

  if (mi < 2) {
    unsigned short* oh = (mi == 0) ? qh : kh;
    unsigned short* ol = (mi == 0) ? ql : kl;
    const int c8 = (t & 15) * 8;
#pragma unroll
    for (int i = 0; i < 8; ++i) {
      const int row = i * 16 + (t >> 4);
      float v8[8];
      *(float4*)(v8)     = *(const float4*)&Cb[row * 128 + c8];
      *(float4*)(v8 + 4) = *(const float4*)&Cb[row * 128 + c8 + 4];
      unsigned short h8[8], l8[8];
#pragma unroll
      for (int j = 0; j < 8; ++j) {
        h8[j] = bf16_rne(v8[j]);
        l8[j] = bf16_rne(v8[j] - bf16f(h8[j]));
      }
      const size_t o = (size_t)(m0 + row) * 128 + c8;
      *(uint4*)(oh + o) = pack8(h8);
      *(uint4*)(ol + o) = pack8(l8);
    }
  } else {
    const int bidx = m0 >> 12, tb0 = m0 & 4095;
    const int tb8 = (t & 15) * 8;
#pragma unroll
    for (int i = 0; i < 8; ++i) {
      const int h = i * 16 + (t >> 4);
      float v8[8];
#pragma unroll
      for (int j = 0; j < 8; ++j) v8[j] = Cb[(tb8 + j) * 128 + h];
      unsigned short h8[8], l8[8];
#pragma unroll
      for (int j = 0; j < 8; ++j) {
        h8[j] = bf16_rne(v8[j]);
        l8[j] = bf16_rne(v8[j] - bf16f(h8[j]));
      }
      const size_t o = ((size_t)bidx * 128 + h) * 4096 + tb0 + tb8;
      *(uint4*)(vTh + o) = pack8(h8);
      *(uint4*)(vTl + o) = pack8(l8);
    }
  }
}

// ---------------------------------------------------------------------------
// attn: flash attention, BQ=64 (4 waves x 16 q-rows), BK=64, kv-split-4.
// Block bx -> (pj = bx>>2, s = bx&3); passes qb = pj then 63-pj (balanced).
// K/V staged via global_load_lds (pre-swizzled source, linear dest).
// All LDS tiles XOR-swizzled; P in per-wave swizzled region (no barrier).
// ---------------------------------------------------------------------------
__global__ __launch_bounds__(256, 2) void attn(
    const unsigned short* __restrict__ qh, const unsigned short* __restrict__ ql,
    const unsigned short* __restrict__ kh, const unsigned short* __restrict__ kl,
    const unsigned short* __restrict__ vTh, const unsigned short* __restrict__ vTl,
    float* __restrict__ OP, float* __restrict__ ML) {
  __shared__ __align__(16) unsigned short sm[40960];  // 80 KB exactly -> 2 blocks/CU
  unsigned short* KhL = sm;            // [64][128] swz
  unsigned short* KlL = sm + 8192;
  unsigned short* VhL = sm + 16384;    // [128][64] swz (h-major)
  unsigned short* VlL = sm + 24576;
  unsigned short* PhL = sm + 32768;    // [4 waves][16][64] swz
  unsigned short* PlL = sm + 36864;

  const int b = blockIdx.y, bx = blockIdx.x;
  const int pj = bx >> 2, s = bx & 3;
  const int t = threadIdx.x, w = t >> 6, l = t & 63, g = l >> 4, lm = l & 15;
  const int sw8 = (lm & 7) << 3;
  const size_t bT = (size_t)b * 4096;
  const f32x4 zf = {0.f, 0.f, 0.f, 0.f};

  // per-lane K staging source pieces: block j covers K rows 4j..4j+3
  const int krow_l = l >> 4;          // 0..3 within block
  const int kh8 = (l & 15) * 8;
  // V: block j covers V h-rows 8j..8j+7
  const int vrow_l = l >> 3;          // 0..7 within block
  const int vk8 = (l & 7) * 8;

  for (int pass = 0; pass < 2; ++pass) {
    const int qb = pass ? (63 - pj) : pj;
    const int q0 = qb * 64;
    const int part = b * 256 + qb * 4 + s;

    bf16x8 qfh[4], qfl[4];
    const size_t qoff = (bT + q0 + w * 16 + lm) * 128;
#pragma unroll
    for (int ks = 0; ks < 4; ++ks) {
      qfh[ks] = *(const bf16x8*)(qh + qoff + ks * 32 + g * 8);
      qfl[ks] = *(const bf16x8*)(ql + qoff + ks * 32 + g * 8);
    }

    f32x4 o[8];
#pragma unroll
    for (int n = 0; n < 8; ++n) o[n] = zf;
    float mrow = -1e30f, lrow = 0.f;
    const int qg = q0 + w * 16 + lm;
    const int nt = qb + 1;   // BK=64 tiles

    for (int ti = s; ti < nt; ti += 4) {
      const int t0 = ti * 64;
      __syncthreads();   // previous tile/pass done reading LDS
      // ---- stage K[64][128] and V[128][64] hi/lo via global_load_lds ----
#pragma unroll
      for (int i = 0; i < 4; ++i) {
        const int j = w * 4 + i;                    // 1KB block 0..15
        const int krow = 4 * j + krow_l;
        const size_t kgo = (bT + t0 + krow) * 128 + (kh8 ^ ((krow & 7) << 3));
        gld16(kh + kgo, KhL + j * 512);
        gld16(kl + kgo, KlL + j * 512);
        const int hrow = 8 * j + vrow_l;
        const size_t vgo = ((size_t)b * 128 + hrow) * 4096 + t0 + (vk8 ^ ((hrow & 7) << 3));
        gld16(vTh + vgo, VhL + j * 512);
        gld16(vTl + vgo, VlL + j * 512);
      }
      __syncthreads();   // vmcnt(0) drain + all waves staged

      // ---- S^T = K * Q^T (split 3-pass): [64 kv][16 q] per wave ----
      f32x4 sa[4] = {zf, zf, zf, zf};
      __builtin_amdgcn_s_setprio(1);
#pragma unroll
      for (int ks = 0; ks < 4; ++ks) {
        const int kb = (ks * 32 + g * 8) ^ sw8;
#pragma unroll
        for (int m = 0; m < 4; ++m) {
          const bf16x8 kf = *(const bf16x8*)&KhL[(m * 16 + lm) * 128 + kb];
          const bf16x8 lf = *(const bf16x8*)&KlL[(m * 16 + lm) * 128 + kb];
          sa[m] = MFMA16(kf, qfh[ks], sa[m]);
          sa[m] = MFMA16(kf, qfl[ks], sa[m]);
          sa[m] = MFMA16(lf, qfh[ks], sa[m]);
        }
      }
      __builtin_amdgcn_s_setprio(0);

      // ---- online softmax: lane owns q-row qg; kv = t0+16m+4g+r ----
      float pv_[16];
      float mt = -1e30f;
#pragma unroll
      for (int m = 0; m < 4; ++m)
#pragma unroll
        for (int r = 0; r < 4; ++r) {
          const int kvg = t0 + m * 16 + g * 4 + r;
          const float sv = (kvg <= qg) ? sa[m][r] * SM_SCALE : -1e30f;
          pv_[m * 4 + r] = sv;
          mt = fmaxf(mt, sv);
        }
      mt = fmaxf(mt, __shfl_xor(mt, 16));
      mt = fmaxf(mt, __shfl_xor(mt, 32));
      const float mnew = fmaxf(mrow, mt);
      const float sc = __expf(mrow - mnew);
      float lsum = 0.f;
#pragma unroll
      for (int j = 0; j < 16; ++j) {
        const float pe = (pv_[j] > -9e29f) ? __expf(pv_[j] - mnew) : 0.f;
        pv_[j] = pe;
        lsum += pe;
      }
      lsum += __shfl_xor(lsum, 16);
      lsum += __shfl_xor(lsum, 32);
      lrow = lrow * sc + lsum;
      mrow = mnew;
      float scr[4];
#pragma unroll
      for (int r = 0; r < 4; ++r) scr[r] = __shfl(sc, g * 4 + r);
#pragma unroll
      for (int n = 0; n < 8; ++n)
#pragma unroll
        for (int r = 0; r < 4; ++r) o[n][r] *= scr[r];

      // ---- P split hi/lo -> per-wave swizzled LDS (no barrier needed) ----
      const int wb = w * 1024;
#pragma unroll
      for (int m = 0; m < 4; ++m)
#pragma unroll
        for (int j2 = 0; j2 < 2; ++j2) {
          const int kv0 = m * 16 + g * 4 + j2 * 2;
          const float p0f = pv_[m * 4 + j2 * 2];
          const float p1f = pv_[m * 4 + j2 * 2 + 1];
          ushort2 h2, l2;
          h2.x = bf16_rne(p0f); l2.x = bf16_rne(p0f - bf16f(h2.x));
          h2.y = bf16_rne(p1f); l2.y = bf16_rne(p1f - bf16f(h2.y));
          *(ushort2*)&PhL[wb + lm * 64 + (kv0 ^ sw8)] = h2;
          *(ushort2*)&PlL[wb + lm * 64 + (kv0 ^ sw8)] = l2;
        }
      const bf16x8 pAh0 = *(const bf16x8*)&PhL[wb + lm * 64 + ((g * 8) ^ sw8)];
      const bf16x8 pAl0 = *(const bf16x8*)&PlL[wb + lm * 64 + ((g * 8) ^ sw8)];
      const bf16x8 pAh1 = *(const bf16x8*)&PhL[wb + lm * 64 + ((32 + g * 8) ^ sw8)];
      const bf16x8 pAl1 = *(const bf16x8*)&PlL[wb + lm * 64 + ((32 + g * 8) ^ sw8)];

      // ---- O += P * V (split 3-pass, 2 k-halves) ----
      __builtin_amdgcn_s_setprio(1);
#pragma unroll
      for (int n = 0; n < 8; ++n) {
        const int vb = (n * 16 + lm) * 64;
        const bf16x8 vh0 = *(const bf16x8*)&VhL[vb + ((g * 8) ^ sw8)];
        const bf16x8 vl0 = *(const bf16x8*)&VlL[vb + ((g * 8) ^ sw8)];
        o[n] = MFMA16(pAh0, vh0, o[n]);
        o[n] = MFMA16(pAh0, vl0, o[n]);
        o[n] = MFMA16(pAl0, vh0, o[n]);
        const bf16x8 vh1 = *(const bf16x8*)&VhL[vb + ((32 + g * 8) ^ sw8)];
        const bf16x8 vl1 = *(const bf16x8*)&VlL[vb + ((32 + g * 8) ^ sw8)];
        o[n] = MFMA16(pAh1, vh1, o[n]);
        o[n] = MFMA16(pAh1, vl1, o[n]);
        o[n] = MFMA16(pAl1, vh1, o[n]);
      }
      __builtin_amdgcn_s_setprio(0);
    } // kv tiles

    // ---- store partials ----
    float* OPp = OP + (size_t)part * 8192;
#pragma unroll
    for (int n = 0; n < 8; ++n)
#pragma unroll
      for (int r = 0; r < 4; ++r)
        OPp[(size_t)(w * 16 + g * 4 + r) * 128 + n * 16 + lm] = o[n][r];
    if (l < 16) {
      ML[((size_t)part * 64 + w * 16 + l) * 2 + 0] = mrow;
      ML[((size_t)part * 64 + w * 16 + l) * 2 + 1] = lrow;
    }
  } // pass
}

// ---------------------------------------------------------------------------
// combine: merge the 4 kv-split partials per q-row. 256 blocks x 256 thr.
// ---------------------------------------------------------------------------
__global__ void combine(const float* __restrict__ OP, const float* __restrict__ ML,
                        float* __restrict__ out) {
  const int x = blockIdx.x;
  const int b = x >> 6, qb = x & 63;
  const int p0 = b * 256 + qb * 4;
  const int t = threadIdx.x;
  const int r = t >> 2, hq = (t & 3) * 32;
  float m[4], ll[4];
#pragma unroll
  for (int s2 = 0; s2 < 4; ++s2) {
    m[s2]  = ML[((size_t)(p0 + s2) * 64 + r) * 2 + 0];
    ll[s2] = ML[((size_t)(p0 + s2) * 64 + r) * 2 + 1];
  }
  const float mx = fmaxf(fmaxf(m[0], m[1]), fmaxf(m[2], m[3]));
  float wgt[4], den = 0.f;
#pragma unroll
  for (int s2 = 0; s2 < 4; ++s2) {
    wgt[s2] = __expf(m[s2] - mx);
    den += wgt[s2] * ll[s2];
  }
  const float inv = 1.f / den;
  float* op = out + ((size_t)(b * 4096 + qb * 64 + r)) * 128 + hq;
#pragma unroll
  for (int j = 0; j < 8; ++j) {
    float ax = 0.f, ay = 0.f, az = 0.f, aw = 0.f;
#pragma unroll
    for (int s2 = 0; s2 < 4; ++s2) {
      const float4 pv = *(const float4*)(OP + ((size_t)(p0 + s2) * 64 + r) * 128 + hq + j * 4);
      ax += wgt[s2] * pv.x; ay += wgt[s2] * pv.y;
      az += wgt[s2] * pv.z; aw += wgt[s2] * pv.w;
    }
    float4 ov; ov.x = ax * inv; ov.y = ay * inv; ov.z = az * inv; ov.w = aw * inv;
    *(float4*)(op + j * 4) = ov;
  }
}

}  // namespace

extern "C" void kernel_launch(void* const* d_in, const int* in_sizes, int n_in,
                              void* d_out, int out_size, void* d_ws, size_t ws_size,
                              hipStream_t stream) {
  // setup_inputs order: x, Wk, bk, Wq, bq, Wv, bv
  const float* x  = (const float*)d_in[0];
  const float* Wk = (const float*)d_in[1];
  const float* bk = (const float*)d_in[2];
  const float* Wq = (const float*)d_in[3];
  const float* bq = (const float*)d_in[4];
  const float* Wv = (const float*)d_in[5];
  const float* bv = (const float*)d_in[6];
  float* out = (float*)d_out;

  // workspace carve (~59.5 MB)
  unsigned short* WtH = (unsigned short*)d_ws;           // 3*128*2048
  unsigned short* WtL = WtH + 786432;
  unsigned short* qh  = WtL + 786432;                    // [16384][128] each
  unsigned short* ql  = qh + 2097152;
  unsigned short* kh  = ql + 2097152;
  unsigned short* kl  = kh + 2097152;
  unsigned short* vTh = kl + 2097152;                    // [4][128][4096]
  unsigned short* vTl = vTh + 2097152;
  float* OP = (float*)(vTl + 2097152);                   // [1024][64][128]
  float* ML = OP + (size_t)1024 * 8192;                  // [1024][64][2]

  prep_w<<<384, 256, 0, stream>>>(Wq, Wk, Wv, WtH, WtL);
  qkv_gemm<<<dim3(3, 128), 256, 0, stream>>>(x, WtH, WtL, bq, bk, bv,
                                             qh, ql, kh, kl, vTh, vTl);
  attn<<<dim3(128, 4), 256, 0, stream>>>(qh, ql, kh, kl, vTh, vTl, OP, ML);
  combine<<<256, 256, 0, stream>>>(OP, ML, out);
}